// Round 6
// baseline (889.778 us; speedup 1.0000x reference)
//
#include <hip/hip_runtime.h>
#include <hip/hip_bf16.h>
#include <stdint.h>

#define MB 8192
#define NL 16384
#define KD 768
#define TOPK 32
#define CAND_NEED 48     // exact-recompute the approx-top-48 (16-rank margin vs bf16 noise)
#define TAU 0.70f        // GEMM-epilogue nomination threshold (rank-48 stat ~0.83 +- 0.013)
#define CAP_MIN 288      // list capacity floor for the fast path (n ~ 157 +- 12.5, ~10 sigma)

typedef short bf16x8 __attribute__((ext_vector_type(8)));
typedef float f32x4 __attribute__((ext_vector_type(4)));
typedef unsigned short ushort_t;

__device__ __forceinline__ short f2bf(float f) {
  unsigned u = __builtin_bit_cast(unsigned, f);
  u = (u + 0x7fffu + ((u >> 16) & 1u)) >> 16;  // RNE
  return (short)u;
}
__device__ __forceinline__ float bf2f(ushort_t u) {
  return __builtin_bit_cast(float, (unsigned)u << 16);
}

// async global->LDS, 16B per lane; LDS dest = wave-uniform base + lane*16
__device__ __forceinline__ void gload16(const ushort_t* g, short* l) {
  __builtin_amdgcn_global_load_lds(
      (const __attribute__((address_space(1))) void*)g,
      (__attribute__((address_space(3))) void*)l, 16, 0, 0);
}

// ============ f32 -> bf16 pre-conversion (16 B/thread) ============
__global__ __launch_bounds__(256) void cvt_bf16(const float* __restrict__ in,
                                                ushort_t* __restrict__ out, int n8) {
  int i = blockIdx.x * 256 + threadIdx.x;
  if (i >= n8) return;
  const float4 v0 = *(const float4*)(in + (size_t)i * 8);
  const float4 v1 = *(const float4*)(in + (size_t)i * 8 + 4);
  bf16x8 p;
  p[0] = f2bf(v0.x); p[1] = f2bf(v0.y); p[2] = f2bf(v0.z); p[3] = f2bf(v0.w);
  p[4] = f2bf(v1.x); p[5] = f2bf(v1.y); p[6] = f2bf(v1.z); p[7] = f2bf(v1.w);
  *(bf16x8*)(out + (size_t)i * 8) = p;
}

// ============ W_dec transpose to packed bf16 rows ============
// Row l (1536 B) layout: pos(d) = d<512 ? (d&255)*2 + (d>>8) : d
__global__ __launch_bounds__(256) void transpose_wdec_pack(const float* __restrict__ W,
                                                           ushort_t* __restrict__ WT) {
  __shared__ float tile[32][33];
  int l0 = blockIdx.x * 32;
  int d0 = blockIdx.y * 32;
  int lx = threadIdx.x;  // 0..31
  for (int i = threadIdx.y; i < 32; i += 8)
    tile[i][lx] = W[(size_t)(d0 + i) * NL + (l0 + lx)];
  __syncthreads();
  int d = d0 + lx;
  int pos = (d < 512) ? ((d & 255) * 2 + (d >> 8)) : d;  // bijective on [0,768)
  for (int i = threadIdx.y; i < 32; i += 8)
    WT[(size_t)(l0 + i) * KD + pos] = (ushort_t)f2bf(tile[lx][i]);
}

#define GBM 128
#define GBN 128
#define GBK 32
#define LDA 32  // 64B rows, 4 x 16B slots; swizzle: phys slot s holds logical s^((row>>1)&3)

// candidate-emitting epilogue (4x4 variant, f32 fallback GEMM)
__device__ __forceinline__ void emit_cands(const f32x4 (&acc)[4][4], int m0, int n0,
                                           int wr64, int wc64, int er, int ec,
                                           int* __restrict__ cnt,
                                           unsigned* __restrict__ lists, int cap) {
#pragma unroll
  for (int i = 0; i < 4; i++)
#pragma unroll
    for (int j = 0; j < 4; j++)
#pragma unroll
      for (int r = 0; r < 4; r++) {
        float v = acc[i][j][r];
        if (v > TAU) {
          int grow = m0 + wr64 + i * 16 + er + r;
          int gcol = n0 + wc64 + j * 16 + ec;
          int pos = atomicAdd(&cnt[grow], 1);
          if (pos < cap)
            lists[(size_t)grow * cap + pos] =
                (unsigned)gcol | ((unsigned)(ushort_t)f2bf(v) << 16);
        }
      }
}

// ============ Encoder GEMM v8: 256x128 tile, 4-phase interleave, delayed vmcnt ======
// Same LDS row layout / slot swizzle / staging math / fragment indexing as the
// proven 128^2 kernel, generalized to 4 A-chunks. Key schedule change: the
// vmcnt(0) drain for tile t's stage happens at the START of tile t+1 (one full
// tile of compute later) via raw s_barrier + inline-asm waitcnt, instead of
// __syncthreads draining loads issued in the SAME iteration. Safety:
//   - per-wave vmcnt(0) before the barrier -> after barrier ALL waves' DMA landed
//   - ds_reads of buf[cur] are consumed by MFMA (compiler lgkm waits) before the
//     barrier; next tile's DMA targets buf[cur^1] and issues after the barrier.
#define PBM 256
#define PBN 128
__global__ __launch_bounds__(256, 2) void encoder_gemm_pre8(const ushort_t* __restrict__ Xb,
                                                            const ushort_t* __restrict__ Wb,
                                                            int* __restrict__ cnt,
                                                            unsigned* __restrict__ lists,
                                                            int cap) {
  __shared__ short Al[2][PBM][LDA];  // 32 KB
  __shared__ short Bl[2][PBN][LDA];  // 16 KB

  const int tid = threadIdx.x;
  const int NBN = NL / PBN;            // 128
  const int GROUP = 8;
  const int NWG = (MB / PBM) * NBN;    // 4096
  const int CPX = NWG / 8;             // 512 (4096 % 8 == 0 -> bijective)
  int bid = (blockIdx.x % 8) * CPX + blockIdx.x / 8;
  int group = bid / (GROUP * NBN);
  int rem = bid % (GROUP * NBN);
  int bm = group * GROUP + (rem % GROUP);   // 0..31
  int bn = rem / GROUP;                     // 0..127
  const int m0 = bm * PBM, n0 = bn * PBN;

  // staging: row r = q*64 + (tid>>2), phys slot s = tid&3;
  // source logical slot = s ^ ((r>>1)&3) = (tid&3) ^ ((tid>>3)&3)  (q*64 ≡ 0 mod 4)
  const int srow = tid >> 2;                        // 0..63
  const int slog = (tid & 3) ^ ((tid >> 3) & 3);
  const int w = tid >> 6;

  const ushort_t* Asrc = Xb + (size_t)(m0 + srow) * KD + slog * 8;
  const ushort_t* Bsrc = Wb + (size_t)(n0 + srow) * KD + slog * 8;

  // A chunk q (q<4): rows q*64 + [16w,16w+16) ; B chunk q (q<2): same on 128 rows
#define STAGEA(BUF, KT, Q)                                                    \
  gload16(Asrc + (size_t)(Q) * 64 * KD + (KT) * GBK,                          \
          &Al[BUF][0][0] + w * 512 + (Q) * 2048);
#define STAGEB(BUF, KT, Q)                                                    \
  gload16(Bsrc + (size_t)(Q) * 64 * KD + (KT) * GBK,                          \
          &Bl[BUF][0][0] + w * 512 + (Q) * 2048);

  const int lane = tid & 63;
  const int wr = (w >> 1) * 128;   // wave row base (0 or 128)
  const int wc = (w & 1) * 64;     // wave col base (0 or 64)
  const int fr = lane & 15;
  const int fkb_sw = (((lane >> 4) ^ ((fr >> 1) & 3))) * 8;

  f32x4 acc[8][4];
#pragma unroll
  for (int i = 0; i < 8; i++)
#pragma unroll
    for (int j = 0; j < 4; j++)
#pragma unroll
      for (int r = 0; r < 4; r++) acc[i][j][r] = 0.f;

  // prologue: stage tile 0 into buf 0 (drained at loop top)
  STAGEA(0, 0, 0) STAGEA(0, 0, 1) STAGEA(0, 0, 2) STAGEA(0, 0, 3)
  STAGEB(0, 0, 0) STAGEB(0, 0, 1)

  const int NT = KD / GBK;  // 24
  int cur = 0;
#define LDAF(I) (*(const bf16x8*)&Al[cur][wr + (I) * 16 + fr][fkb_sw])
#define LDBF(J) (*(const bf16x8*)&Bl[cur][wc + (J) * 16 + fr][fkb_sw])
#define MF(AI, AV, BJ) \
  acc[AI][BJ] = __builtin_amdgcn_mfma_f32_16x16x32_bf16(AV, bg##BJ, acc[AI][BJ], 0, 0, 0);
#define MF8(I0, I1, A0, A1)                                     \
  __builtin_amdgcn_s_setprio(1);                                \
  MF(I0, A0, 0) MF(I0, A0, 1) MF(I0, A0, 2) MF(I0, A0, 3)       \
  MF(I1, A1, 0) MF(I1, A1, 1) MF(I1, A1, 2) MF(I1, A1, 3)       \
  __builtin_amdgcn_s_setprio(0);

  for (int kt = 0; kt < NT; kt++) {
    // drain tile-kt stage (issued one full tile ago -> near-zero stall)
    asm volatile("s_waitcnt vmcnt(0)" ::: "memory");
    __builtin_amdgcn_s_barrier();
    __builtin_amdgcn_sched_barrier(0);
    const int nb = cur ^ 1;
    const bool pre = (kt + 1 < NT);

    // phase 0: stage A0,A1 of next tile; B frags + A rows 0,1
    if (pre) { STAGEA(nb, kt + 1, 0) STAGEA(nb, kt + 1, 1) }
    bf16x8 bg0 = LDBF(0), bg1 = LDBF(1), bg2 = LDBF(2), bg3 = LDBF(3);
    bf16x8 a0 = LDAF(0), a1 = LDAF(1);
    MF8(0, 1, a0, a1)
    // phase 1: stage A2,A3; A rows 2,3
    if (pre) { STAGEA(nb, kt + 1, 2) STAGEA(nb, kt + 1, 3) }
    a0 = LDAF(2); a1 = LDAF(3);
    MF8(2, 3, a0, a1)
    // phase 2: stage B0; A rows 4,5
    if (pre) { STAGEB(nb, kt + 1, 0) }
    a0 = LDAF(4); a1 = LDAF(5);
    MF8(4, 5, a0, a1)
    // phase 3: stage B1; A rows 6,7
    if (pre) { STAGEB(nb, kt + 1, 1) }
    a0 = LDAF(6); a1 = LDAF(7);
    MF8(6, 7, a0, a1)

    cur = nb;
  }
#undef LDAF
#undef LDBF
#undef MF
#undef MF8
#undef STAGEA
#undef STAGEB

  // epilogue: emit candidates (C frag: col=lane&15, row=(lane>>4)*4+r)
  const int er = (lane >> 4) * 4;
  const int ec = lane & 15;
#pragma unroll
  for (int i = 0; i < 8; i++)
#pragma unroll
    for (int j = 0; j < 4; j++)
#pragma unroll
      for (int r = 0; r < 4; r++) {
        float v = acc[i][j][r];
        if (v > TAU) {
          int grow = m0 + wr + i * 16 + er + r;
          int gcol = n0 + wc + j * 16 + ec;
          int pos = atomicAdd(&cnt[grow], 1);
          if (pos < cap)
            lists[(size_t)grow * cap + pos] =
                (unsigned)gcol | ((unsigned)(ushort_t)f2bf(v) << 16);
        }
      }
}

// ============ Encoder GEMM, f32 inputs w/ inline cvt (fallback if ws too small) ============
__global__ __launch_bounds__(256, 4) void encoder_gemm_f32(const float* __restrict__ X,
                                                           const float* __restrict__ Wenc,
                                                           int* __restrict__ cnt,
                                                           unsigned* __restrict__ lists,
                                                           int cap) {
  __shared__ short Al[2][GBM][LDA];
  __shared__ short Bl[2][GBN][LDA];

  const int tid = threadIdx.x;
  const int NBN = NL / GBN;
  const int GROUP = 8;
  int bid = blockIdx.x;
  int group = bid / (GROUP * NBN);
  int rem = bid % (GROUP * NBN);
  int bm = group * GROUP + (rem % GROUP);
  int bn = rem / GROUP;
  const int m0 = bm * GBM, n0 = bn * GBN;

  const int srow = tid >> 2;
  const int skg = tid & 3;
  const int sw8 = (skg ^ ((srow >> 1) & 3)) * 8;

  const float* Abase = X + (size_t)(m0 + srow) * KD + skg * 8;
  const float* Bbase = Wenc + (size_t)(n0 + srow) * KD + skg * 8;

  float4 ra0, ra1, ra2, ra3, rb0, rb1, rb2, rb3;

#define FLOADS(KT)                                         \
  {                                                        \
    const float* ap_ = Abase + (KT) * GBK;                 \
    const float* bp_ = Bbase + (KT) * GBK;                 \
    ra0 = *(const float4*)(ap_);                           \
    ra1 = *(const float4*)(ap_ + 4);                       \
    ra2 = *(const float4*)(ap_ + (size_t)64 * KD);         \
    ra3 = *(const float4*)(ap_ + (size_t)64 * KD + 4);     \
    rb0 = *(const float4*)(bp_);                           \
    rb1 = *(const float4*)(bp_ + 4);                       \
    rb2 = *(const float4*)(bp_ + (size_t)64 * KD);         \
    rb3 = *(const float4*)(bp_ + (size_t)64 * KD + 4);     \
  }

#define CVT8(DST, FA, FB)                                                    \
  {                                                                          \
    bf16x8 p_;                                                               \
    p_[0] = f2bf(FA.x); p_[1] = f2bf(FA.y); p_[2] = f2bf(FA.z);              \
    p_[3] = f2bf(FA.w); p_[4] = f2bf(FB.x); p_[5] = f2bf(FB.y);              \
    p_[6] = f2bf(FB.z); p_[7] = f2bf(FB.w);                                  \
    *(bf16x8*)(DST) = p_;                                                    \
  }

#define FWRITE(BUF)                                      \
  {                                                      \
    CVT8(&Al[BUF][srow][sw8], ra0, ra1);                 \
    CVT8(&Al[BUF][srow + 64][sw8], ra2, ra3);            \
    CVT8(&Bl[BUF][srow][sw8], rb0, rb1);                 \
    CVT8(&Bl[BUF][srow + 64][sw8], rb2, rb3);            \
  }

  const int lane = tid & 63;
  const int w = tid >> 6;
  const int wr64 = (w >> 1) * 64;
  const int wc64 = (w & 1) * 64;
  const int fr = lane & 15;
  const int fkb_sw = (((lane >> 4) ^ ((fr >> 1) & 3))) * 8;

  f32x4 acc[4][4];
#pragma unroll
  for (int i = 0; i < 4; i++)
#pragma unroll
    for (int j = 0; j < 4; j++)
#pragma unroll
      for (int r = 0; r < 4; r++) acc[i][j][r] = 0.f;

  FLOADS(0);
  FWRITE(0);
  __syncthreads();

  const int NT = KD / GBK;
  for (int kt = 0; kt < NT; kt++) {
    const int cur = kt & 1;
    if (kt + 1 < NT) FLOADS(kt + 1);

    bf16x8 af[4], bg[4];
#pragma unroll
    for (int i = 0; i < 4; i++)
      af[i] = *(const bf16x8*)&Al[cur][wr64 + i * 16 + fr][fkb_sw];
#pragma unroll
    for (int j = 0; j < 4; j++)
      bg[j] = *(const bf16x8*)&Bl[cur][wc64 + j * 16 + fr][fkb_sw];

#pragma unroll
    for (int i = 0; i < 4; i++)
#pragma unroll
      for (int j = 0; j < 4; j++)
        acc[i][j] = __builtin_amdgcn_mfma_f32_16x16x32_bf16(af[i], bg[j], acc[i][j], 0, 0, 0);

    if (kt + 1 < NT) FWRITE(cur ^ 1);
    __syncthreads();
  }

  const int er = (lane >> 4) * 4;
  const int ec = lane & 15;
  emit_cands(acc, m0, n0, wr64, wc64, er, ec, cnt, lists, cap);
#undef FLOADS
#undef CVT8
#undef FWRITE
}

// ============ Select + decode (R5 version: best measured, 390 us) ============
__global__ __launch_bounds__(256) void select_decode(const int* __restrict__ cnt,
                                                     const unsigned* __restrict__ lists,
                                                     int cap,
                                                     const float* __restrict__ X,
                                                     const float* __restrict__ Wenc,
                                                     const ushort_t* __restrict__ WdTb,
                                                     const float* __restrict__ Wdec,
                                                     int use_wdt,
                                                     float* __restrict__ Z,
                                                     float* __restrict__ Xhat) {
  __shared__ float xrow[KD];
  __shared__ int cj[512];
  __shared__ float cv[512];
  __shared__ int s48_j[CAND_NEED];
  __shared__ float s48_v[CAND_NEED];
  __shared__ int sel_j[TOPK];
  __shared__ float sel_v[TOPK];
  __shared__ float red_v[256];
  __shared__ int red_i[256];

  const int tid = threadIdx.x;
  const int row = blockIdx.x;
  float* z = Z + (size_t)row * NL;

  if (tid < KD / 4)
    ((float4*)xrow)[tid] = ((const float4*)(X + (size_t)row * KD))[tid];

  const int n = cnt[row];
  const bool fb = (n < CAND_NEED) || (n > cap) || (n > 512);

  if (!fb) {
    for (int i = tid; i < n; i += 256) {
      unsigned e = lists[(size_t)row * cap + i];
      cj[i] = (int)(e & 0xffffu);
      cv[i] = bf2f((ushort_t)(e >> 16));
    }
    __syncthreads();
    // narrow: approx rank by (value desc, index asc); keep ranks < 48
    for (int i = tid; i < n; i += 256) {
      float vi = cv[i];
      int ji = cj[i];
      int r = 0;
      for (int c = 0; c < n; c++) {
        float vc = cv[c];
        r += (int)((vc > vi) || (vc == vi && cj[c] < ji));
      }
      if (r < CAND_NEED) { s48_j[r] = ji; s48_v[r] = vi; }
    }
    __syncthreads();
    // exact f32 recompute: ONE THREAD per candidate, sequential k=0..767 fmaf
    // (bit-identical rounding chain — certified against np ranking; DO NOT REORDER)
    if (tid < CAND_NEED) {
      const float4* wr4 = (const float4*)(Wenc + (size_t)s48_j[tid] * KD);
      float s = 0.f;
#pragma unroll 8
      for (int k4 = 0; k4 < KD / 4; k4++) {
        float4 w = wr4[k4];
        s = fmaf(xrow[4 * k4 + 0], w.x, s);
        s = fmaf(xrow[4 * k4 + 1], w.y, s);
        s = fmaf(xrow[4 * k4 + 2], w.z, s);
        s = fmaf(xrow[4 * k4 + 3], w.w, s);
      }
      s48_v[tid] = s;
    } else if (tid >= 64) {
      // waves 1-3 zero this block's z row (non-temporal: never re-read)
      const f32x4 zf = {0.f, 0.f, 0.f, 0.f};
      f32x4* z4 = (f32x4*)z;
      for (int i = tid - 64; i < NL / 4; i += 192)
        __builtin_nontemporal_store(zf, z4 + i);
    }
    __syncthreads();
    // exact top-32 by (value desc, index asc)
    if (tid < CAND_NEED) {
      float vi = s48_v[tid];
      int ji = s48_j[tid];
      int r = 0;
      for (int c = 0; c < CAND_NEED; c++) {
        float vc = s48_v[c];
        r += (int)((vc > vi) || (vc == vi && s48_j[c] < ji));
      }
      if (r < TOPK) { sel_j[r] = ji; sel_v[r] = fmaxf(vi, 0.f); }
    }
    __syncthreads();
    if (tid < TOPK) z[sel_j[tid]] = sel_v[tid];
  } else {
    // ---- rare exact fallback: dense recompute via z row as scratch, 32 argmax passes
    for (int j = tid; j < NL; j += 256) {
      const float* wr = Wenc + (size_t)j * KD;
      float s = 0.f;
      for (int k = 0; k < KD; k++) s = fmaf(xrow[k], wr[k], s);
      z[j] = fmaxf(s, 0.f);
    }
    __syncthreads();
    for (int t = 0; t < TOPK; t++) {
      float bm = -1.f;
      int bi = NL;
      for (int j = tid; j < NL; j += 256) {
        float v = z[j];
        if (v > bm || (v == bm && j < bi)) { bm = v; bi = j; }
      }
      red_v[tid] = bm;
      red_i[tid] = bi;
      __syncthreads();
      for (int s2 = 128; s2 > 0; s2 >>= 1) {
        if (tid < s2) {
          float v2 = red_v[tid + s2];
          int i2 = red_i[tid + s2];
          if (v2 > red_v[tid] || (v2 == red_v[tid] && i2 < red_i[tid])) {
            red_v[tid] = v2;
            red_i[tid] = i2;
          }
        }
        __syncthreads();
      }
      if (tid == 0) {
        sel_j[t] = red_i[0];
        sel_v[t] = red_v[0];
        z[red_i[0]] = -1.f;  // sentinel below any relu'd value
      }
      __syncthreads();
    }
    for (int j = tid; j < NL; j += 256) z[j] = 0.f;
    __syncthreads();
    if (tid < TOPK) z[sel_j[tid]] = sel_v[tid];
  }
  __syncthreads();

  // ---- fused decode, 4-way ILP; packed WdTb rows (1x4B + 1x2B per candidate)
  float a00 = 0.f, a01 = 0.f, a02 = 0.f;
  float a10 = 0.f, a11 = 0.f, a12 = 0.f;
  float a20 = 0.f, a21 = 0.f, a22 = 0.f;
  float a30 = 0.f, a31 = 0.f, a32 = 0.f;
  if (use_wdt) {
#define DEC(P0, P1, P2, TT)                                   \
    {                                                         \
      float v = sel_v[TT];                                    \
      const ushort_t* wr = WdTb + (size_t)sel_j[TT] * KD;     \
      unsigned u = ((const unsigned*)wr)[tid];                \
      P0 = fmaf(v, bf2f((ushort_t)(u & 0xffffu)), P0);        \
      P1 = fmaf(v, bf2f((ushort_t)(u >> 16)), P1);            \
      P2 = fmaf(v, bf2f(wr[512 + tid]), P2);                  \
    }
    for (int t = 0; t < TOPK; t += 4) {
      DEC(a00, a01, a02, t)
      DEC(a10, a11, a12, t + 1)
      DEC(a20, a21, a22, t + 2)
      DEC(a30, a31, a32, t + 3)
    }
#undef DEC
  } else {
    for (int t = 0; t < TOPK; t++) {
      float v = sel_v[t];
      const float* wc = Wdec + sel_j[t];
      a00 = fmaf(v, wc[(size_t)tid * NL], a00);
      a01 = fmaf(v, wc[(size_t)(tid + 256) * NL], a01);
      a02 = fmaf(v, wc[(size_t)(tid + 512) * NL], a02);
    }
  }
  float* xo = Xhat + (size_t)row * KD;
  __builtin_nontemporal_store((a00 + a10) + (a20 + a30), xo + tid);
  __builtin_nontemporal_store((a01 + a11) + (a21 + a31), xo + tid + 256);
  __builtin_nontemporal_store((a02 + a12) + (a22 + a32), xo + tid + 512);
}

// ============ launch ============
extern "C" void kernel_launch(void* const* d_in, const int* in_sizes, int n_in,
                              void* d_out, int out_size, void* d_ws, size_t ws_size,
                              hipStream_t stream) {
  const float* x = (const float*)d_in[0];
  const float* Wenc = (const float*)d_in[1];
  const float* Wdec = (const float*)d_in[2];
  // d_in[3] is k (always 32 for this problem)

  float* xhat = (float*)d_out;
  float* z = (float*)d_out + (size_t)MB * KD;

  const size_t cnt_b = (size_t)MB * sizeof(int);              // 32 KB
  const size_t wsh_b = (size_t)NL * KD * sizeof(ushort_t);    // 25.2 MB (Wb, then WdTb)
  const size_t xb_b = (size_t)MB * KD * sizeof(ushort_t);     // 12.6 MB
  const size_t entry = sizeof(unsigned);                      // 4 B packed list entries

  char* ws = (char*)d_ws;
  int* cnt = (int*)ws;
  size_t off = cnt_b;

  int use_pre = 0, use_wdt = 0, cap = 1;
  ushort_t* Wsh = nullptr;
  ushort_t* Xb = nullptr;
  unsigned* lists = nullptr;

  if (ws_size >= cnt_b + wsh_b + xb_b + (size_t)MB * entry * CAP_MIN) {
    // tier A: bf16 global_load_lds GEMM; Wsh time-shared (Wb during GEMM, WdTb after)
    use_pre = 1; use_wdt = 1;
    Wsh = (ushort_t*)(ws + off); off += wsh_b;
    Xb = (ushort_t*)(ws + off); off += xb_b;
    lists = (unsigned*)(ws + off);
    size_t c = (ws_size - off) / ((size_t)MB * entry);
    cap = (int)(c > 512 ? 512 : c);
  } else if (ws_size >= cnt_b + wsh_b + (size_t)MB * entry * CAP_MIN) {
    // tier B: f32 GEMM with inline cvt; packed WdTb decode
    use_wdt = 1;
    Wsh = (ushort_t*)(ws + off); off += wsh_b;
    lists = (unsigned*)(ws + off);
    size_t c = (ws_size - off) / ((size_t)MB * entry);
    cap = (int)(c > 512 ? 512 : c);
  } else {
    // tier C: degraded — strided Wdec decode; whatever list fits (fb catches overflow)
    lists = (unsigned*)(ws + off);
    size_t avail = (ws_size > off) ? (ws_size - off) : 0;
    size_t c = avail / ((size_t)MB * entry);
    cap = (int)(c > 512 ? 512 : c);
    if (cap < 1) cap = 1;
  }

  // zero candidate counters only (z rows are zeroed inside select_decode)
  hipMemsetAsync(cnt, 0, cnt_b, stream);

  if (use_pre) {
    int nx8 = MB * KD / 8, nw8 = NL * KD / 8;
    cvt_bf16<<<(nx8 + 255) / 256, 256, 0, stream>>>(x, Xb, nx8);
    cvt_bf16<<<(nw8 + 255) / 256, 256, 0, stream>>>(Wenc, Wsh, nw8);
    encoder_gemm_pre8<<<(MB / PBM) * (NL / PBN), 256, 0, stream>>>(Xb, Wsh, cnt, lists, cap);
    // transpose AFTER the GEMM: Wsh is reused (stream-serialized, so no race)
    dim3 g(NL / 32, KD / 32);
    transpose_wdec_pack<<<g, dim3(32, 8), 0, stream>>>(Wdec, Wsh);
  } else {
    if (use_wdt) {
      dim3 g(NL / 32, KD / 32);
      transpose_wdec_pack<<<g, dim3(32, 8), 0, stream>>>(Wdec, Wsh);
    }
    encoder_gemm_f32<<<(MB / GBM) * (NL / GBN), 256, 0, stream>>>(x, Wenc, cnt, lists, cap);
  }
  select_decode<<<MB, 256, 0, stream>>>(cnt, lists, cap, x, Wenc, Wsh, Wdec, use_wdt,
                                        z, xhat);
}

// Round 7
// 744.893 us; speedup vs baseline: 1.1945x; 1.1945x over previous
//
#include <hip/hip_runtime.h>
#include <hip/hip_bf16.h>
#include <stdint.h>

#define MB 8192
#define NL 16384
#define KD 768
#define TOPK 32
#define CAND_NEED 48     // exact-recompute the approx-top-48 (16-rank margin vs bf16 noise)
#define TAU 0.70f        // GEMM-epilogue nomination threshold (rank-48 stat ~0.83 +- 0.013)
#define CAP_MIN 288      // list capacity floor for the fast path (n ~ 157 +- 12.5, ~10 sigma)

typedef short bf16x8 __attribute__((ext_vector_type(8)));
typedef float f32x4 __attribute__((ext_vector_type(4)));
typedef unsigned short ushort_t;

__device__ __forceinline__ short f2bf(float f) {
  unsigned u = __builtin_bit_cast(unsigned, f);
  u = (u + 0x7fffu + ((u >> 16) & 1u)) >> 16;  // RNE
  return (short)u;
}
__device__ __forceinline__ float bf2f(ushort_t u) {
  return __builtin_bit_cast(float, (unsigned)u << 16);
}

// async global->LDS, 16B per lane; LDS dest = wave-uniform base + lane*16
__device__ __forceinline__ void gload16(const ushort_t* g, short* l) {
  __builtin_amdgcn_global_load_lds(
      (const __attribute__((address_space(1))) void*)g,
      (__attribute__((address_space(3))) void*)l, 16, 0, 0);
}

// ============ f32 -> bf16 pre-conversion (16 B/thread) ============
__global__ __launch_bounds__(256) void cvt_bf16(const float* __restrict__ in,
                                                ushort_t* __restrict__ out, int n8) {
  int i = blockIdx.x * 256 + threadIdx.x;
  if (i >= n8) return;
  const float4 v0 = *(const float4*)(in + (size_t)i * 8);
  const float4 v1 = *(const float4*)(in + (size_t)i * 8 + 4);
  bf16x8 p;
  p[0] = f2bf(v0.x); p[1] = f2bf(v0.y); p[2] = f2bf(v0.z); p[3] = f2bf(v0.w);
  p[4] = f2bf(v1.x); p[5] = f2bf(v1.y); p[6] = f2bf(v1.z); p[7] = f2bf(v1.w);
  *(bf16x8*)(out + (size_t)i * 8) = p;
}

// ============ W_dec transpose to packed bf16 rows ============
// Row l (1536 B) layout: pos(d) = d<512 ? (d&255)*2 + (d>>8) : d
__global__ __launch_bounds__(256) void transpose_wdec_pack(const float* __restrict__ W,
                                                           ushort_t* __restrict__ WT) {
  __shared__ float tile[32][33];
  int l0 = blockIdx.x * 32;
  int d0 = blockIdx.y * 32;
  int lx = threadIdx.x;  // 0..31
  for (int i = threadIdx.y; i < 32; i += 8)
    tile[i][lx] = W[(size_t)(d0 + i) * NL + (l0 + lx)];
  __syncthreads();
  int d = d0 + lx;
  int pos = (d < 512) ? ((d & 255) * 2 + (d >> 8)) : d;  // bijective on [0,768)
  for (int i = threadIdx.y; i < 32; i += 8)
    WT[(size_t)(l0 + i) * KD + pos] = (ushort_t)f2bf(tile[lx][i]);
}

#define GBM 128
#define GBN 128
#define GBK 32
#define LDA 32  // 64B rows, 4 x 16B slots; swizzle: phys slot s holds logical s^((row>>1)&3)

// candidate-emitting epilogue (shared by GEMM variants)
__device__ __forceinline__ void emit_cands(const f32x4 (&acc)[4][4], int m0, int n0,
                                           int wr64, int wc64, int er, int ec,
                                           int* __restrict__ cnt,
                                           unsigned* __restrict__ lists, int cap) {
#pragma unroll
  for (int i = 0; i < 4; i++)
#pragma unroll
    for (int j = 0; j < 4; j++)
#pragma unroll
      for (int r = 0; r < 4; r++) {
        float v = acc[i][j][r];
        if (v > TAU) {
          int grow = m0 + wr64 + i * 16 + er + r;
          int gcol = n0 + wc64 + j * 16 + ec;
          int pos = atomicAdd(&cnt[grow], 1);
          if (pos < cap)
            lists[(size_t)grow * cap + pos] =
                (unsigned)gcol | ((unsigned)(ushort_t)f2bf(v) << 16);
        }
      }
}

// ============ Encoder GEMM v2: proven 128^2 geometry + T4 counted-vmcnt pipeline ====
// Identical LDS layout / slot swizzle / staging math / fragment indexing to the
// R5 kernel (4 blocks/CU, 16 waves/CU). Only the schedule changed:
//   2-deep prefetch; loop top waits s_waitcnt vmcnt(4) (tile kt landed, tile
//   kt+1's 4 loads STAY IN FLIGHT — never drain to 0 in steady state) + raw
//   s_barrier; after compute, a second raw s_barrier frees buf[kt&1] and tile
//   kt+2 is staged into it. Each stage has a FULL K-step (~ >> HBM latency) in
//   flight before its wait -> near-zero stall.
// Safety: waitcnt precedes barrier (cross-wave DMA visibility); per-wave ds_reads
// complete before their consuming MFMAs (SSA deps), so the second barrier
// guarantees no wave still reads buf[kt&1] when the DMA overwrites it; vmcnt is
// per-wave FIFO so vmcnt(4) == "my tile-kt loads done". Last tile peels to vmcnt(0).
__global__ __launch_bounds__(256, 4) void encoder_gemm_pre2(const ushort_t* __restrict__ Xb,
                                                            const ushort_t* __restrict__ Wb,
                                                            int* __restrict__ cnt,
                                                            unsigned* __restrict__ lists,
                                                            int cap) {
  __shared__ short Al[2][GBM][LDA];
  __shared__ short Bl[2][GBN][LDA];

  const int tid = threadIdx.x;
  const int NBN = NL / GBN;   // 128
  const int GROUP = 8;
  const int NWG = (MB / GBM) * NBN;  // 8192
  const int CPX = NWG / 8;           // 1024 (8192 % 8 == 0 -> bijective)
  int bid = (blockIdx.x % 8) * CPX + blockIdx.x / 8;
  int group = bid / (GROUP * NBN);
  int rem = bid % (GROUP * NBN);
  int bm = group * GROUP + (rem % GROUP);
  int bn = rem / GROUP;
  const int m0 = bm * GBM, n0 = bn * GBN;

  const int srow = tid >> 2;                        // 0..63
  const int slog = (tid & 3) ^ ((tid >> 3) & 3);    // inverse-swizzled source slot
  const int w = tid >> 6;

  const ushort_t* Asrc = Xb + (size_t)(m0 + srow) * KD + slog * 8;
  const ushort_t* Bsrc = Wb + (size_t)(n0 + srow) * KD + slog * 8;

#define STAGE(BUF, KT)                                              \
  {                                                                 \
    const int koff_ = (KT) * GBK;                                   \
    short* la_ = &Al[BUF][0][0] + w * 512;                          \
    short* lb_ = &Bl[BUF][0][0] + w * 512;                          \
    gload16(Asrc + koff_, la_);                                     \
    gload16(Asrc + (size_t)64 * KD + koff_, la_ + 2048);            \
    gload16(Bsrc + koff_, lb_);                                     \
    gload16(Bsrc + (size_t)64 * KD + koff_, lb_ + 2048);            \
  }

  const int lane = tid & 63;
  const int wr64 = (w >> 1) * 64;
  const int wc64 = (w & 1) * 64;
  const int fr = lane & 15;
  const int fkb_sw = (((lane >> 4) ^ ((fr >> 1) & 3))) * 8;

  f32x4 acc[4][4];
#pragma unroll
  for (int i = 0; i < 4; i++)
#pragma unroll
    for (int j = 0; j < 4; j++)
#pragma unroll
      for (int r = 0; r < 4; r++) acc[i][j][r] = 0.f;

  // 2-deep prologue: tiles 0 and 1 in flight (8 loads/thread)
  STAGE(0, 0);
  STAGE(1, 1);

  const int NT = KD / GBK;  // 24
  for (int kt = 0; kt < NT; kt++) {
    // tile kt's 4 loads done; tile kt+1's 4 remain in flight (counted, not 0)
    if (kt + 1 < NT) {
      asm volatile("s_waitcnt vmcnt(4)" ::: "memory");
    } else {
      asm volatile("s_waitcnt vmcnt(0)" ::: "memory");
    }
    __builtin_amdgcn_s_barrier();

    const int cur = kt & 1;
    bf16x8 af[4], bg[4];
#pragma unroll
    for (int i = 0; i < 4; i++)
      af[i] = *(const bf16x8*)&Al[cur][wr64 + i * 16 + fr][fkb_sw];
#pragma unroll
    for (int j = 0; j < 4; j++)
      bg[j] = *(const bf16x8*)&Bl[cur][wc64 + j * 16 + fr][fkb_sw];

#pragma unroll
    for (int i = 0; i < 4; i++)
#pragma unroll
      for (int j = 0; j < 4; j++)
        acc[i][j] = __builtin_amdgcn_mfma_f32_16x16x32_bf16(af[i], bg[j], acc[i][j], 0, 0, 0);

    // all waves' ds_reads of buf[cur] are complete (consumed by MFMAs above)
    __builtin_amdgcn_s_barrier();
    if (kt + 2 < NT) STAGE(cur, kt + 2);  // overwrite the just-freed buffer
  }

  const int er = (lane >> 4) * 4;
  const int ec = lane & 15;
  emit_cands(acc, m0, n0, wr64, wc64, er, ec, cnt, lists, cap);
#undef STAGE
}

// ============ Encoder GEMM, f32 inputs w/ inline cvt (fallback if ws too small) ============
__global__ __launch_bounds__(256, 4) void encoder_gemm_f32(const float* __restrict__ X,
                                                           const float* __restrict__ Wenc,
                                                           int* __restrict__ cnt,
                                                           unsigned* __restrict__ lists,
                                                           int cap) {
  __shared__ short Al[2][GBM][LDA];
  __shared__ short Bl[2][GBN][LDA];

  const int tid = threadIdx.x;
  const int NBN = NL / GBN;
  const int GROUP = 8;
  int bid = blockIdx.x;
  int group = bid / (GROUP * NBN);
  int rem = bid % (GROUP * NBN);
  int bm = group * GROUP + (rem % GROUP);
  int bn = rem / GROUP;
  const int m0 = bm * GBM, n0 = bn * GBN;

  const int srow = tid >> 2;
  const int skg = tid & 3;
  const int sw8 = (skg ^ ((srow >> 1) & 3)) * 8;

  const float* Abase = X + (size_t)(m0 + srow) * KD + skg * 8;
  const float* Bbase = Wenc + (size_t)(n0 + srow) * KD + skg * 8;

  float4 ra0, ra1, ra2, ra3, rb0, rb1, rb2, rb3;

#define FLOADS(KT)                                         \
  {                                                        \
    const float* ap_ = Abase + (KT) * GBK;                 \
    const float* bp_ = Bbase + (KT) * GBK;                 \
    ra0 = *(const float4*)(ap_);                           \
    ra1 = *(const float4*)(ap_ + 4);                       \
    ra2 = *(const float4*)(ap_ + (size_t)64 * KD);         \
    ra3 = *(const float4*)(ap_ + (size_t)64 * KD + 4);     \
    rb0 = *(const float4*)(bp_);                           \
    rb1 = *(const float4*)(bp_ + 4);                       \
    rb2 = *(const float4*)(bp_ + (size_t)64 * KD);         \
    rb3 = *(const float4*)(bp_ + (size_t)64 * KD + 4);     \
  }

#define CVT8(DST, FA, FB)                                                    \
  {                                                                          \
    bf16x8 p_;                                                               \
    p_[0] = f2bf(FA.x); p_[1] = f2bf(FA.y); p_[2] = f2bf(FA.z);              \
    p_[3] = f2bf(FA.w); p_[4] = f2bf(FB.x); p_[5] = f2bf(FB.y);              \
    p_[6] = f2bf(FB.z); p_[7] = f2bf(FB.w);                                  \
    *(bf16x8*)(DST) = p_;                                                    \
  }

#define FWRITE(BUF)                                      \
  {                                                      \
    CVT8(&Al[BUF][srow][sw8], ra0, ra1);                 \
    CVT8(&Al[BUF][srow + 64][sw8], ra2, ra3);            \
    CVT8(&Bl[BUF][srow][sw8], rb0, rb1);                 \
    CVT8(&Bl[BUF][srow + 64][sw8], rb2, rb3);            \
  }

  const int lane = tid & 63;
  const int w = tid >> 6;
  const int wr64 = (w >> 1) * 64;
  const int wc64 = (w & 1) * 64;
  const int fr = lane & 15;
  const int fkb_sw = (((lane >> 4) ^ ((fr >> 1) & 3))) * 8;

  f32x4 acc[4][4];
#pragma unroll
  for (int i = 0; i < 4; i++)
#pragma unroll
    for (int j = 0; j < 4; j++)
#pragma unroll
      for (int r = 0; r < 4; r++) acc[i][j][r] = 0.f;

  FLOADS(0);
  FWRITE(0);
  __syncthreads();

  const int NT = KD / GBK;
  for (int kt = 0; kt < NT; kt++) {
    const int cur = kt & 1;
    if (kt + 1 < NT) FLOADS(kt + 1);

    bf16x8 af[4], bg[4];
#pragma unroll
    for (int i = 0; i < 4; i++)
      af[i] = *(const bf16x8*)&Al[cur][wr64 + i * 16 + fr][fkb_sw];
#pragma unroll
    for (int j = 0; j < 4; j++)
      bg[j] = *(const bf16x8*)&Bl[cur][wc64 + j * 16 + fr][fkb_sw];

#pragma unroll
    for (int i = 0; i < 4; i++)
#pragma unroll
      for (int j = 0; j < 4; j++)
        acc[i][j] = __builtin_amdgcn_mfma_f32_16x16x32_bf16(af[i], bg[j], acc[i][j], 0, 0, 0);

    if (kt + 1 < NT) FWRITE(cur ^ 1);
    __syncthreads();
  }

  const int er = (lane >> 4) * 4;
  const int ec = lane & 15;
  emit_cands(acc, m0, n0, wr64, wc64, er, ec, cnt, lists, cap);
#undef FLOADS
#undef CVT8
#undef FWRITE
}

// ============ Select + decode (R5 version: best measured, 390 us) ============
__global__ __launch_bounds__(256) void select_decode(const int* __restrict__ cnt,
                                                     const unsigned* __restrict__ lists,
                                                     int cap,
                                                     const float* __restrict__ X,
                                                     const float* __restrict__ Wenc,
                                                     const ushort_t* __restrict__ WdTb,
                                                     const float* __restrict__ Wdec,
                                                     int use_wdt,
                                                     float* __restrict__ Z,
                                                     float* __restrict__ Xhat) {
  __shared__ float xrow[KD];
  __shared__ int cj[512];
  __shared__ float cv[512];
  __shared__ int s48_j[CAND_NEED];
  __shared__ float s48_v[CAND_NEED];
  __shared__ int sel_j[TOPK];
  __shared__ float sel_v[TOPK];
  __shared__ float red_v[256];
  __shared__ int red_i[256];

  const int tid = threadIdx.x;
  const int row = blockIdx.x;
  float* z = Z + (size_t)row * NL;

  if (tid < KD / 4)
    ((float4*)xrow)[tid] = ((const float4*)(X + (size_t)row * KD))[tid];

  const int n = cnt[row];
  const bool fb = (n < CAND_NEED) || (n > cap) || (n > 512);

  if (!fb) {
    for (int i = tid; i < n; i += 256) {
      unsigned e = lists[(size_t)row * cap + i];
      cj[i] = (int)(e & 0xffffu);
      cv[i] = bf2f((ushort_t)(e >> 16));
    }
    __syncthreads();
    // narrow: approx rank by (value desc, index asc); keep ranks < 48
    for (int i = tid; i < n; i += 256) {
      float vi = cv[i];
      int ji = cj[i];
      int r = 0;
      for (int c = 0; c < n; c++) {
        float vc = cv[c];
        r += (int)((vc > vi) || (vc == vi && cj[c] < ji));
      }
      if (r < CAND_NEED) { s48_j[r] = ji; s48_v[r] = vi; }
    }
    __syncthreads();
    // exact f32 recompute: ONE THREAD per candidate, sequential k=0..767 fmaf
    // (bit-identical rounding chain — certified against np ranking; DO NOT REORDER)
    if (tid < CAND_NEED) {
      const float4* wr4 = (const float4*)(Wenc + (size_t)s48_j[tid] * KD);
      float s = 0.f;
#pragma unroll 8
      for (int k4 = 0; k4 < KD / 4; k4++) {
        float4 w = wr4[k4];
        s = fmaf(xrow[4 * k4 + 0], w.x, s);
        s = fmaf(xrow[4 * k4 + 1], w.y, s);
        s = fmaf(xrow[4 * k4 + 2], w.z, s);
        s = fmaf(xrow[4 * k4 + 3], w.w, s);
      }
      s48_v[tid] = s;
    } else if (tid >= 64) {
      // waves 1-3 zero this block's z row (non-temporal: never re-read)
      const f32x4 zf = {0.f, 0.f, 0.f, 0.f};
      f32x4* z4 = (f32x4*)z;
      for (int i = tid - 64; i < NL / 4; i += 192)
        __builtin_nontemporal_store(zf, z4 + i);
    }
    __syncthreads();
    // exact top-32 by (value desc, index asc)
    if (tid < CAND_NEED) {
      float vi = s48_v[tid];
      int ji = s48_j[tid];
      int r = 0;
      for (int c = 0; c < CAND_NEED; c++) {
        float vc = s48_v[c];
        r += (int)((vc > vi) || (vc == vi && s48_j[c] < ji));
      }
      if (r < TOPK) { sel_j[r] = ji; sel_v[r] = fmaxf(vi, 0.f); }
    }
    __syncthreads();
    if (tid < TOPK) z[sel_j[tid]] = sel_v[tid];
  } else {
    // ---- rare exact fallback: dense recompute via z row as scratch, 32 argmax passes
    for (int j = tid; j < NL; j += 256) {
      const float* wr = Wenc + (size_t)j * KD;
      float s = 0.f;
      for (int k = 0; k < KD; k++) s = fmaf(xrow[k], wr[k], s);
      z[j] = fmaxf(s, 0.f);
    }
    __syncthreads();
    for (int t = 0; t < TOPK; t++) {
      float bm = -1.f;
      int bi = NL;
      for (int j = tid; j < NL; j += 256) {
        float v = z[j];
        if (v > bm || (v == bm && j < bi)) { bm = v; bi = j; }
      }
      red_v[tid] = bm;
      red_i[tid] = bi;
      __syncthreads();
      for (int s2 = 128; s2 > 0; s2 >>= 1) {
        if (tid < s2) {
          float v2 = red_v[tid + s2];
          int i2 = red_i[tid + s2];
          if (v2 > red_v[tid] || (v2 == red_v[tid] && i2 < red_i[tid])) {
            red_v[tid] = v2;
            red_i[tid] = i2;
          }
        }
        __syncthreads();
      }
      if (tid == 0) {
        sel_j[t] = red_i[0];
        sel_v[t] = red_v[0];
        z[red_i[0]] = -1.f;  // sentinel below any relu'd value
      }
      __syncthreads();
    }
    for (int j = tid; j < NL; j += 256) z[j] = 0.f;
    __syncthreads();
    if (tid < TOPK) z[sel_j[tid]] = sel_v[tid];
  }
  __syncthreads();

  // ---- fused decode, 4-way ILP; packed WdTb rows (1x4B + 1x2B per candidate)
  float a00 = 0.f, a01 = 0.f, a02 = 0.f;
  float a10 = 0.f, a11 = 0.f, a12 = 0.f;
  float a20 = 0.f, a21 = 0.f, a22 = 0.f;
  float a30 = 0.f, a31 = 0.f, a32 = 0.f;
  if (use_wdt) {
#define DEC(P0, P1, P2, TT)                                   \
    {                                                         \
      float v = sel_v[TT];                                    \
      const ushort_t* wr = WdTb + (size_t)sel_j[TT] * KD;     \
      unsigned u = ((const unsigned*)wr)[tid];                \
      P0 = fmaf(v, bf2f((ushort_t)(u & 0xffffu)), P0);        \
      P1 = fmaf(v, bf2f((ushort_t)(u >> 16)), P1);            \
      P2 = fmaf(v, bf2f(wr[512 + tid]), P2);                  \
    }
    for (int t = 0; t < TOPK; t += 4) {
      DEC(a00, a01, a02, t)
      DEC(a10, a11, a12, t + 1)
      DEC(a20, a21, a22, t + 2)
      DEC(a30, a31, a32, t + 3)
    }
#undef DEC
  } else {
    for (int t = 0; t < TOPK; t++) {
      float v = sel_v[t];
      const float* wc = Wdec + sel_j[t];
      a00 = fmaf(v, wc[(size_t)tid * NL], a00);
      a01 = fmaf(v, wc[(size_t)(tid + 256) * NL], a01);
      a02 = fmaf(v, wc[(size_t)(tid + 512) * NL], a02);
    }
  }
  float* xo = Xhat + (size_t)row * KD;
  __builtin_nontemporal_store((a00 + a10) + (a20 + a30), xo + tid);
  __builtin_nontemporal_store((a01 + a11) + (a21 + a31), xo + tid + 256);
  __builtin_nontemporal_store((a02 + a12) + (a22 + a32), xo + tid + 512);
}

// ============ launch ============
extern "C" void kernel_launch(void* const* d_in, const int* in_sizes, int n_in,
                              void* d_out, int out_size, void* d_ws, size_t ws_size,
                              hipStream_t stream) {
  const float* x = (const float*)d_in[0];
  const float* Wenc = (const float*)d_in[1];
  const float* Wdec = (const float*)d_in[2];
  // d_in[3] is k (always 32 for this problem)

  float* xhat = (float*)d_out;
  float* z = (float*)d_out + (size_t)MB * KD;

  const size_t cnt_b = (size_t)MB * sizeof(int);              // 32 KB
  const size_t wsh_b = (size_t)NL * KD * sizeof(ushort_t);    // 25.2 MB (Wb, then WdTb)
  const size_t xb_b = (size_t)MB * KD * sizeof(ushort_t);     // 12.6 MB
  const size_t entry = sizeof(unsigned);                      // 4 B packed list entries

  char* ws = (char*)d_ws;
  int* cnt = (int*)ws;
  size_t off = cnt_b;

  int use_pre = 0, use_wdt = 0, cap = 1;
  ushort_t* Wsh = nullptr;
  ushort_t* Xb = nullptr;
  unsigned* lists = nullptr;

  if (ws_size >= cnt_b + wsh_b + xb_b + (size_t)MB * entry * CAP_MIN) {
    // tier A: bf16 global_load_lds GEMM; Wsh time-shared (Wb during GEMM, WdTb after)
    use_pre = 1; use_wdt = 1;
    Wsh = (ushort_t*)(ws + off); off += wsh_b;
    Xb = (ushort_t*)(ws + off); off += xb_b;
    lists = (unsigned*)(ws + off);
    size_t c = (ws_size - off) / ((size_t)MB * entry);
    cap = (int)(c > 512 ? 512 : c);
  } else if (ws_size >= cnt_b + wsh_b + (size_t)MB * entry * CAP_MIN) {
    // tier B: f32 GEMM with inline cvt; packed WdTb decode
    use_wdt = 1;
    Wsh = (ushort_t*)(ws + off); off += wsh_b;
    lists = (unsigned*)(ws + off);
    size_t c = (ws_size - off) / ((size_t)MB * entry);
    cap = (int)(c > 512 ? 512 : c);
  } else {
    // tier C: degraded — strided Wdec decode; whatever list fits (fb catches overflow)
    lists = (unsigned*)(ws + off);
    size_t avail = (ws_size > off) ? (ws_size - off) : 0;
    size_t c = avail / ((size_t)MB * entry);
    cap = (int)(c > 512 ? 512 : c);
    if (cap < 1) cap = 1;
  }

  // zero candidate counters only (z rows are zeroed inside select_decode)
  hipMemsetAsync(cnt, 0, cnt_b, stream);

  if (use_pre) {
    int nx8 = MB * KD / 8, nw8 = NL * KD / 8;
    cvt_bf16<<<(nx8 + 255) / 256, 256, 0, stream>>>(x, Xb, nx8);
    cvt_bf16<<<(nw8 + 255) / 256, 256, 0, stream>>>(Wenc, Wsh, nw8);
    encoder_gemm_pre2<<<(MB / GBM) * (NL / GBN), 256, 0, stream>>>(Xb, Wsh, cnt, lists, cap);
    // transpose AFTER the GEMM: Wsh is reused (stream-serialized, so no race)
    dim3 g(NL / 32, KD / 32);
    transpose_wdec_pack<<<g, dim3(32, 8), 0, stream>>>(Wdec, Wsh);
  } else {
    if (use_wdt) {
      dim3 g(NL / 32, KD / 32);
      transpose_wdec_pack<<<g, dim3(32, 8), 0, stream>>>(Wdec, Wsh);
    }
    encoder_gemm_f32<<<(MB / GBM) * (NL / GBN), 256, 0, stream>>>(x, Wenc, cnt, lists, cap);
  }
  select_decode<<<MB, 256, 0, stream>>>(cnt, lists, cap, x, Wenc, Wsh, Wdec, use_wdt,
                                        z, xhat);
}